// Round 17
// baseline (679.375 us; speedup 1.0000x reference)
//
#include <hip/hip_runtime.h>
#include <hip/hip_bf16.h>
#include <stdint.h>

// B=32768 queries, M=4096 memory rows, D=128.
//   logits = Q @ M^T ; attn = softmax(logits) ; out = attn @ M
// v16: v15's barrier-free LDS-free fp16 kernel at 4 waves/SIMD.
// v15 post-mortem: VGPR_Count=124 (allocator sank the K/V prefetches) ->
// per-visit chain ~16 serial L2 loads x 225cyc ~ 3600 cyc = the 96us
// invariant. Latency-bound chain + un-batchable loads -> TLP, not ILP:
// the kernel already fits the 128-reg cap for 4 waves/SIMD, so launch
// 1024 blocks (4-way M-split, part = bx&3 so co-resident blocks share
// the same K/V part for L1/L2 locality). Parts 1-3 store partial O in
// fp16 (ws 2+24+1=27MB); part 0 fp32 direct in d_out; 4-way merge.

typedef float    f32x16 __attribute__((ext_vector_type(16)));
typedef _Float16 f16x8  __attribute__((ext_vector_type(8)));
typedef uint32_t u32;

#define D_DIM 128
#define B_ROWS 32768
#define KTILE_HW 4096     // halfwords per 32-row fragment tile (8 KB)
#define PART_TILES 32     // tiles per block (128 / 4 parts)

#if __has_builtin(__builtin_amdgcn_exp2f)
#define EXP2F(x) __builtin_amdgcn_exp2f(x)
#else
#define EXP2F(x) exp2f(x)
#endif

__device__ __forceinline__ uint16_t f32_to_f16_bits(float x) {
    _Float16 h = (_Float16)x;
    uint16_t r; __builtin_memcpy(&r, &h, 2);
    return r;
}
__device__ __forceinline__ float2 unpack_h2(u32 w) {
    _Float16 h[2]; __builtin_memcpy(h, &w, 4);
    return make_float2((float)h[0], (float)h[1]);
}

// ---------------------------------------------------------------------------
// Prep: memory -> fragment-linear fp16 K and V regions in d_ws (1 MB each).
//   K frag kk: kws[mt*4096 + kk*512 + lane*8 + e]
//              = memory[mt*32 + (lane&31)][kk*16 + (lane>>5)*8 + e]
//   V frag f=ks*4+dt: vws[mt*4096 + f*512 + lane*8 + e]
//              = memory[mt*32 + ks*16 + (lane>>5)*8 + e][dt*32 + (lane&31)]
// ---------------------------------------------------------------------------
__global__ void prep_frags(const float* __restrict__ mem,
                           uint16_t* __restrict__ kws,
                           uint16_t* __restrict__ vws) {
    int t = blockIdx.x * blockDim.x + threadIdx.x;  // 0..65535
    int lane = t & 63;
    int fi = t >> 6;                                // 0..1023
    int f8 = fi & 7, mt = fi >> 3;
    size_t base = (size_t)mt * KTILE_HW;
    {   // K fragment
        int m  = mt * 32 + (lane & 31);
        int d0 = f8 * 16 + (lane >> 5) * 8;
        const float* src = mem + (size_t)m * D_DIM + d0;
        #pragma unroll
        for (int e = 0; e < 8; ++e)
            kws[base + f8 * 512 + lane * 8 + e] = f32_to_f16_bits(src[e]);
    }
    {   // V^T fragment
        int dt = fi & 3, ks = (fi >> 2) & 1;
        int d  = dt * 32 + (lane & 31);
        int m0 = mt * 32 + ks * 16 + (lane >> 5) * 8;
        #pragma unroll
        for (int e = 0; e < 8; ++e)
            vws[base + f8 * 512 + lane * 8 + e] =
                f32_to_f16_bits(mem[(size_t)(m0 + e) * D_DIM + d]);
    }
}

// ---------------------------------------------------------------------------
// Main kernel: 1024 blocks x 256 threads (4 waves), no LDS, no barriers,
// 4 blocks/CU = 4 waves/SIMD. Block bx: q-chunk bx>>2, memory part bx&3
// (32 tiles; co-resident blocks share a part -> L1/L2 locality).
// ---------------------------------------------------------------------------

#define MFMA_F16(a_, b_, c_) __builtin_amdgcn_mfma_f32_32x32x16_f16(a_, b_, c_, 0, 0, 0)

#define KLOAD(kp_, KH) do {                                                   \
    _Pragma("unroll")                                                         \
    for (int kk_ = 0; kk_ < 8; ++kk_)                                         \
        KH[kk_] = *(const f16x8*)((kp_) + kk_ * 512);                         \
} while (0)

#define VLOAD(vp_, VF) do {                                                   \
    _Pragma("unroll")                                                         \
    for (int f_ = 0; f_ < 8; ++f_)                                            \
        VF[f_] = *(const f16x8*)((vp_) + f_ * 512);                           \
} while (0)

// QK^T on register-resident K: two 4-deep chains -> s_.
#define QK(KH, s_) do {                                                       \
    f32x16 sA_, sB_;                                                          \
    _Pragma("unroll")                                                         \
    for (int i_ = 0; i_ < 16; ++i_) { sA_[i_] = 0.f; sB_[i_] = 0.f; }         \
    __builtin_amdgcn_s_setprio(1);                                            \
    sA_ = MFMA_F16(KH[0], qh[0], sA_);                                        \
    sB_ = MFMA_F16(KH[1], qh[1], sB_);                                        \
    sA_ = MFMA_F16(KH[2], qh[2], sA_);                                        \
    sB_ = MFMA_F16(KH[3], qh[3], sB_);                                        \
    sA_ = MFMA_F16(KH[4], qh[4], sA_);                                        \
    sB_ = MFMA_F16(KH[5], qh[5], sB_);                                        \
    sA_ = MFMA_F16(KH[6], qh[6], sA_);                                        \
    sB_ = MFMA_F16(KH[7], qh[7], sB_);                                        \
    __builtin_amdgcn_s_setprio(0);                                            \
    s_ = sA_ + sB_;                                                           \
} while (0)

// Online softmax on s_ (Sᵀ layout: q=lane&31) then PV with register V frags.
#define SMX_PV(s_, VF) do {                                                   \
    float a0=fmaxf(s_[0],s_[1]),  a1=fmaxf(s_[2],s_[3]);                      \
    float a2=fmaxf(s_[4],s_[5]),  a3=fmaxf(s_[6],s_[7]);                      \
    float a4=fmaxf(s_[8],s_[9]),  a5=fmaxf(s_[10],s_[11]);                    \
    float a6=fmaxf(s_[12],s_[13]),a7=fmaxf(s_[14],s_[15]);                    \
    float tmax = fmaxf(fmaxf(fmaxf(a0,a1),fmaxf(a2,a3)),                      \
                       fmaxf(fmaxf(a4,a5),fmaxf(a6,a7)));                     \
    tmax = fmaxf(tmax, __shfl_xor(tmax, 32));                                 \
    if (__any(tmax > m_run + 8.0f)) {     /* defer-max (T13) */               \
        float mn = fmaxf(m_run, tmax);                                        \
        float fr = EXP2F(m_run - mn);                                         \
        m_run = mn; l_run *= fr;                                              \
        _Pragma("unroll")                                                     \
        for (int r_ = 0; r_ < 16; ++r_) {                                     \
            O0[r_] *= fr; O1[r_] *= fr; O2[r_] *= fr; O3[r_] *= fr;           \
        }                                                                     \
    }                                                                         \
    _Pragma("unroll")                                                         \
    for (int r_ = 0; r_ < 16; ++r_) s_[r_] = EXP2F(s_[r_] - m_run);           \
    { float q0s=s_[0]+s_[1],  q1s=s_[2]+s_[3],  q2s=s_[4]+s_[5],  q3s=s_[6]+s_[7];   \
      float q4s=s_[8]+s_[9],  q5s=s_[10]+s_[11],q6s=s_[12]+s_[13],q7s=s_[14]+s_[15]; \
      l_run += ((q0s+q1s)+(q2s+q3s)) + ((q4s+q5s)+(q6s+q7s)); }               \
    u32 c_[8];                                                                \
    _Pragma("unroll")                                                         \
    for (int j_ = 0; j_ < 8; ++j_)                                            \
        asm("v_cvt_pkrtz_f16_f32 %0, %1, %2"                                  \
            : "=v"(c_[j_]) : "v"(s_[2*j_]), "v"(s_[2*j_+1]));                 \
    asm("v_permlane32_swap_b32 %0, %1" : "+v"(c_[0]), "+v"(c_[2]));           \
    asm("v_permlane32_swap_b32 %0, %1" : "+v"(c_[1]), "+v"(c_[3]));           \
    asm("v_permlane32_swap_b32 %0, %1" : "+v"(c_[4]), "+v"(c_[6]));           \
    asm("v_permlane32_swap_b32 %0, %1" : "+v"(c_[5]), "+v"(c_[7]));           \
    f16x8 pf0_, pf1_;                                                         \
    { u32 w_[4] = {c_[0], c_[1], c_[2], c_[3]}; __builtin_memcpy(&pf0_, w_, 16); } \
    { u32 w_[4] = {c_[4], c_[5], c_[6], c_[7]}; __builtin_memcpy(&pf1_, w_, 16); } \
    __builtin_amdgcn_s_setprio(1);                                            \
    O0 = MFMA_F16(VF[0], pf0_, O0);                                           \
    O1 = MFMA_F16(VF[1], pf0_, O1);                                           \
    O2 = MFMA_F16(VF[2], pf0_, O2);                                           \
    O3 = MFMA_F16(VF[3], pf0_, O3);                                           \
    O0 = MFMA_F16(VF[4], pf1_, O0);                                           \
    O1 = MFMA_F16(VF[5], pf1_, O1);                                           \
    O2 = MFMA_F16(VF[6], pf1_, O2);                                           \
    O3 = MFMA_F16(VF[7], pf1_, O3);                                           \
    __builtin_amdgcn_s_setprio(0);                                            \
} while (0)

#define PSTORE_F32(Ot_, t_) do {                                              \
    _Pragma("unroll")                                                         \
    for (int g_ = 0; g_ < 4; ++g_) {                                          \
        float4 v_ = { Ot_[4*g_+0], Ot_[4*g_+1], Ot_[4*g_+2], Ot_[4*g_+3] };   \
        int d_ = (t_) * 32 + 8 * g_ + 4 * hi32;                               \
        *(float4*)(prow32 + d_) = v_;                                         \
    }                                                                         \
} while (0)

#define PSTORE_F16(Ot_, t_) do {                                              \
    _Pragma("unroll")                                                         \
    for (int g_ = 0; g_ < 4; ++g_) {                                          \
        u32 lo_, hi_;                                                         \
        asm("v_cvt_pkrtz_f16_f32 %0, %1, %2"                                  \
            : "=v"(lo_) : "v"(Ot_[4*g_+0]), "v"(Ot_[4*g_+1]));                \
        asm("v_cvt_pkrtz_f16_f32 %0, %1, %2"                                  \
            : "=v"(hi_) : "v"(Ot_[4*g_+2]), "v"(Ot_[4*g_+3]));                \
        int d_ = (t_) * 32 + 8 * g_ + 4 * hi32;                               \
        *(uint2*)(prow16 + d_) = make_uint2(lo_, hi_);                        \
    }                                                                         \
} while (0)

__global__ __launch_bounds__(256, 4)
void attn_main(const float* __restrict__ qin,
               const uint16_t* __restrict__ kws,
               const uint16_t* __restrict__ vws,
               float* __restrict__ out0,       // part-0 un-normalized O (= d_out)
               uint16_t* __restrict__ pout16,  // [3][B_ROWS][128] fp16 parts 1-3
               float2* __restrict__ pml) {     // [4][B_ROWS] (m, l)
    const int lane = threadIdx.x & 63;
    const int wave = threadIdx.x >> 6;
    const int part = blockIdx.x & 3;
    const int tilebase = part * PART_TILES;
    const int q0   = (blockIdx.x >> 2) * 128 + wave * 32;
    const int qrow = q0 + (lane & 31);
    const int hi32 = lane >> 5;

    // Q prep: scale by log2(e), convert to fp16 (B-frag of Sᵀ MFMA).
    f16x8 qh[8];
    {
        const float LOG2E = 1.44269504088896340736f;
        #pragma unroll
        for (int kk = 0; kk < 8; ++kk) {
            const float* src = qin + (size_t)qrow * D_DIM + kk * 16 + hi32 * 8;
            float4 a = *(const float4*)(src);
            float4 b = *(const float4*)(src + 4);
            float xs[8] = {a.x, a.y, a.z, a.w, b.x, b.y, b.z, b.w};
            #pragma unroll
            for (int e = 0; e < 8; ++e)
                qh[kk][e] = (_Float16)(xs[e] * LOG2E);
        }
    }

    f32x16 O0, O1, O2, O3;
    #pragma unroll
    for (int i = 0; i < 16; ++i) { O0[i]=0.f; O1[i]=0.f; O2[i]=0.f; O3[i]=0.f; }
    float m_run = -1e30f, l_run = 0.f;

    const uint16_t* kp = kws + (size_t)tilebase * KTILE_HW + lane * 8;
    const uint16_t* vp = vws + (size_t)tilebase * KTILE_HW + lane * 8;

    f16x8 khA[8], khB[8];
    KLOAD(kp, khA);                     // K(0)

    // 2 tiles per iteration; K register-double-buffered one tile ahead,
    // V issued at visit start (L2 latency covered by QK+softmax).
    #pragma unroll 1
    for (int tp = 0; tp < PART_TILES / 2; ++tp) {
        const int t = 2 * tp;
        {   // ---- tile t (K in khA) ----
            f16x8 vf[8];
            VLOAD(vp + (size_t)t * KTILE_HW, vf);
            KLOAD(kp + (size_t)(t + 1) * KTILE_HW, khB);   // prefetch K(t+1)
            f32x16 s;
            QK(khA, s);
            SMX_PV(s, vf);
        }
        {   // ---- tile t+1 (K in khB) ----
            f16x8 vf[8];
            VLOAD(vp + (size_t)(t + 1) * KTILE_HW, vf);
            if (t + 2 < PART_TILES)
                KLOAD(kp + (size_t)(t + 2) * KTILE_HW, khA);  // prefetch K(t+2)
            f32x16 s;
            QK(khB, s);
            SMX_PV(s, vf);
        }
    }

    // ---- partial store (un-normalized O, plus m,l) ----
    l_run += __shfl_xor(l_run, 32);     // pair-lane partial sums
    if (part == 0) {
        float* prow32 = out0 + (size_t)qrow * D_DIM;
        PSTORE_F32(O0, 0); PSTORE_F32(O1, 1);
        PSTORE_F32(O2, 2); PSTORE_F32(O3, 3);
    } else {
        uint16_t* prow16 = pout16 + ((size_t)(part - 1) * B_ROWS + qrow) * D_DIM;
        PSTORE_F16(O0, 0); PSTORE_F16(O1, 1);
        PSTORE_F16(O2, 2); PSTORE_F16(O3, 3);
    }
    if (lane < 32) {
        pml[(size_t)part * B_ROWS + qrow] = make_float2(m_run, l_run);
    }
}

// ---------------------------------------------------------------------------
// Merge: out = sum_p(P_p * w_p) / sum_p(l_p * w_p), w_p = exp2(m_p - max).
// P0 fp32 in d_out (in-place); P1-3 fp16 in ws.
// ---------------------------------------------------------------------------
__global__ __launch_bounds__(256)
void merge_parts(const uint16_t* __restrict__ pout16,
                 const float2* __restrict__ pml,
                 float* __restrict__ out) {
    int idx  = blockIdx.x * 256 + threadIdx.x;   // 0 .. 2^20-1
    int row  = idx >> 5;
    int c4   = idx & 31;
    float2 a = pml[row];
    float2 b = pml[B_ROWS + row];
    float2 c = pml[2 * B_ROWS + row];
    float2 d = pml[3 * B_ROWS + row];
    float mn = fmaxf(fmaxf(a.x, b.x), fmaxf(c.x, d.x));
    float wa = EXP2F(a.x - mn), wb = EXP2F(b.x - mn);
    float wc = EXP2F(c.x - mn), wd = EXP2F(d.x - mn);
    float rinv = 1.0f / (a.y * wa + b.y * wb + c.y * wc + d.y * wd);

    float4* O = (float4*)(out + (size_t)row * D_DIM) + c4;
    float4 p0 = *O;
    float acc[4] = { p0.x * wa, p0.y * wa, p0.z * wa, p0.w * wa };
    #pragma unroll
    for (int p = 0; p < 3; ++p) {
        const uint16_t* src = pout16 + ((size_t)p * B_ROWS + row) * D_DIM + c4 * 4;
        uint2 q = *(const uint2*)src;
        float2 lo = unpack_h2(q.x), hi = unpack_h2(q.y);
        float w = (p == 0) ? wb : (p == 1 ? wc : wd);
        acc[0] += lo.x * w; acc[1] += lo.y * w;
        acc[2] += hi.x * w; acc[3] += hi.y * w;
    }
    float4 v = { acc[0] * rinv, acc[1] * rinv, acc[2] * rinv, acc[3] * rinv };
    *O = v;
}

extern "C" void kernel_launch(void* const* d_in, const int* in_sizes, int n_in,
                              void* d_out, int out_size, void* d_ws, size_t ws_size,
                              hipStream_t stream) {
    const float* local_stats = (const float*)d_in[0];   // [32768,128] f32
    const float* memory      = (const float*)d_in[1];   // [4096,128]  f32
    float* out = (float*)d_out;                         // [32768,128] f32

    // ws layout: K frags 1MB | V frags 1MB | fp16 parts 1-3 24MB | pml 1MB
    uint16_t* kws    = (uint16_t*)d_ws;
    uint16_t* vws    = kws + 128 * KTILE_HW;
    uint16_t* pout16 = (uint16_t*)((char*)d_ws + 2 * 1024 * 1024);
    float2*   pml    = (float2*)((char*)pout16 + (size_t)3 * B_ROWS * D_DIM * 2);

    prep_frags<<<256, 256, 0, stream>>>(memory, kws, vws);
    attn_main<<<1024, 256, 0, stream>>>(local_stats, kws, vws, out, pout16, pml);
    merge_parts<<<4096, 256, 0, stream>>>(pout16, pml, out);
}

// Round 18
// 115.781 us; speedup vs baseline: 5.8677x; 5.8677x over previous
//
#include <hip/hip_runtime.h>
#include <hip/hip_bf16.h>
#include <stdint.h>

// B=32768 queries, M=4096 memory rows, D=128.
//   logits = Q @ M^T ; attn = softmax(logits) ; out = attn @ M
// v17: v16's 4-way M-split with the PROVEN register bound.
// v16 failed because __launch_bounds__(256,4) silently capped VGPR at 64
// -> 1.7GB spill traffic. v15's identical kernel body under (256,2)
// compiles to 124 VGPR <= 128, so FOUR 256-thread blocks fit per CU by
// resource usage alone; v15 only had 2 blocks/CU because the grid was 512.
// v17: 1024 blocks (part = bx&3; co-resident blocks share a part since
// 256%4==0 -> L2 locality), launch_bounds(256,2) untouched. Tests the
// serial-L2-latency-chain theory (3600cyc/visit) via TLP 2->4.

typedef float    f32x16 __attribute__((ext_vector_type(16)));
typedef _Float16 f16x8  __attribute__((ext_vector_type(8)));
typedef uint32_t u32;

#define D_DIM 128
#define B_ROWS 32768
#define KTILE_HW 4096     // halfwords per 32-row fragment tile (8 KB)
#define PART_TILES 32     // tiles per block (128 / 4 parts)

#if __has_builtin(__builtin_amdgcn_exp2f)
#define EXP2F(x) __builtin_amdgcn_exp2f(x)
#else
#define EXP2F(x) exp2f(x)
#endif

__device__ __forceinline__ uint16_t f32_to_f16_bits(float x) {
    _Float16 h = (_Float16)x;
    uint16_t r; __builtin_memcpy(&r, &h, 2);
    return r;
}
__device__ __forceinline__ float2 unpack_h2(u32 w) {
    _Float16 h[2]; __builtin_memcpy(h, &w, 4);
    return make_float2((float)h[0], (float)h[1]);
}

// ---------------------------------------------------------------------------
// Prep: memory -> fragment-linear fp16 K and V regions in d_ws (1 MB each).
//   K frag kk: kws[mt*4096 + kk*512 + lane*8 + e]
//              = memory[mt*32 + (lane&31)][kk*16 + (lane>>5)*8 + e]
//   V frag f=ks*4+dt: vws[mt*4096 + f*512 + lane*8 + e]
//              = memory[mt*32 + ks*16 + (lane>>5)*8 + e][dt*32 + (lane&31)]
// ---------------------------------------------------------------------------
__global__ void prep_frags(const float* __restrict__ mem,
                           uint16_t* __restrict__ kws,
                           uint16_t* __restrict__ vws) {
    int t = blockIdx.x * blockDim.x + threadIdx.x;  // 0..65535
    int lane = t & 63;
    int fi = t >> 6;                                // 0..1023
    int f8 = fi & 7, mt = fi >> 3;
    size_t base = (size_t)mt * KTILE_HW;
    {   // K fragment
        int m  = mt * 32 + (lane & 31);
        int d0 = f8 * 16 + (lane >> 5) * 8;
        const float* src = mem + (size_t)m * D_DIM + d0;
        #pragma unroll
        for (int e = 0; e < 8; ++e)
            kws[base + f8 * 512 + lane * 8 + e] = f32_to_f16_bits(src[e]);
    }
    {   // V^T fragment
        int dt = fi & 3, ks = (fi >> 2) & 1;
        int d  = dt * 32 + (lane & 31);
        int m0 = mt * 32 + ks * 16 + (lane >> 5) * 8;
        #pragma unroll
        for (int e = 0; e < 8; ++e)
            vws[base + f8 * 512 + lane * 8 + e] =
                f32_to_f16_bits(mem[(size_t)(m0 + e) * D_DIM + d]);
    }
}

// ---------------------------------------------------------------------------
// Main kernel: 1024 blocks x 256 threads (4 waves), no LDS, no barriers.
// Resource-based residency: 124 VGPR, 0 LDS -> 4 blocks/CU (4 waves/SIMD).
// Block bx: q-chunk bx>>2, memory part bx&3 (32 tiles).
// ---------------------------------------------------------------------------

#define MFMA_F16(a_, b_, c_) __builtin_amdgcn_mfma_f32_32x32x16_f16(a_, b_, c_, 0, 0, 0)

#define KLOAD(kp_, KH) do {                                                   \
    _Pragma("unroll")                                                         \
    for (int kk_ = 0; kk_ < 8; ++kk_)                                         \
        KH[kk_] = *(const f16x8*)((kp_) + kk_ * 512);                         \
} while (0)

#define VLOAD(vp_, VF) do {                                                   \
    _Pragma("unroll")                                                         \
    for (int f_ = 0; f_ < 8; ++f_)                                            \
        VF[f_] = *(const f16x8*)((vp_) + f_ * 512);                           \
} while (0)

// QK^T on register-resident K: two 4-deep chains -> s_.
#define QK(KH, s_) do {                                                       \
    f32x16 sA_, sB_;                                                          \
    _Pragma("unroll")                                                         \
    for (int i_ = 0; i_ < 16; ++i_) { sA_[i_] = 0.f; sB_[i_] = 0.f; }         \
    __builtin_amdgcn_s_setprio(1);                                            \
    sA_ = MFMA_F16(KH[0], qh[0], sA_);                                        \
    sB_ = MFMA_F16(KH[1], qh[1], sB_);                                        \
    sA_ = MFMA_F16(KH[2], qh[2], sA_);                                        \
    sB_ = MFMA_F16(KH[3], qh[3], sB_);                                        \
    sA_ = MFMA_F16(KH[4], qh[4], sA_);                                        \
    sB_ = MFMA_F16(KH[5], qh[5], sB_);                                        \
    sA_ = MFMA_F16(KH[6], qh[6], sA_);                                        \
    sB_ = MFMA_F16(KH[7], qh[7], sB_);                                        \
    __builtin_amdgcn_s_setprio(0);                                            \
    s_ = sA_ + sB_;                                                           \
} while (0)

// Online softmax on s_ (Sᵀ layout: q=lane&31) then PV with register V frags.
#define SMX_PV(s_, VF) do {                                                   \
    float a0=fmaxf(s_[0],s_[1]),  a1=fmaxf(s_[2],s_[3]);                      \
    float a2=fmaxf(s_[4],s_[5]),  a3=fmaxf(s_[6],s_[7]);                      \
    float a4=fmaxf(s_[8],s_[9]),  a5=fmaxf(s_[10],s_[11]);                    \
    float a6=fmaxf(s_[12],s_[13]),a7=fmaxf(s_[14],s_[15]);                    \
    float tmax = fmaxf(fmaxf(fmaxf(a0,a1),fmaxf(a2,a3)),                      \
                       fmaxf(fmaxf(a4,a5),fmaxf(a6,a7)));                     \
    tmax = fmaxf(tmax, __shfl_xor(tmax, 32));                                 \
    if (__any(tmax > m_run + 8.0f)) {     /* defer-max (T13) */               \
        float mn = fmaxf(m_run, tmax);                                        \
        float fr = EXP2F(m_run - mn);                                         \
        m_run = mn; l_run *= fr;                                              \
        _Pragma("unroll")                                                     \
        for (int r_ = 0; r_ < 16; ++r_) {                                     \
            O0[r_] *= fr; O1[r_] *= fr; O2[r_] *= fr; O3[r_] *= fr;           \
        }                                                                     \
    }                                                                         \
    _Pragma("unroll")                                                         \
    for (int r_ = 0; r_ < 16; ++r_) s_[r_] = EXP2F(s_[r_] - m_run);           \
    { float q0s=s_[0]+s_[1],  q1s=s_[2]+s_[3],  q2s=s_[4]+s_[5],  q3s=s_[6]+s_[7];   \
      float q4s=s_[8]+s_[9],  q5s=s_[10]+s_[11],q6s=s_[12]+s_[13],q7s=s_[14]+s_[15]; \
      l_run += ((q0s+q1s)+(q2s+q3s)) + ((q4s+q5s)+(q6s+q7s)); }               \
    u32 c_[8];                                                                \
    _Pragma("unroll")                                                         \
    for (int j_ = 0; j_ < 8; ++j_)                                            \
        asm("v_cvt_pkrtz_f16_f32 %0, %1, %2"                                  \
            : "=v"(c_[j_]) : "v"(s_[2*j_]), "v"(s_[2*j_+1]));                 \
    asm("v_permlane32_swap_b32 %0, %1" : "+v"(c_[0]), "+v"(c_[2]));           \
    asm("v_permlane32_swap_b32 %0, %1" : "+v"(c_[1]), "+v"(c_[3]));           \
    asm("v_permlane32_swap_b32 %0, %1" : "+v"(c_[4]), "+v"(c_[6]));           \
    asm("v_permlane32_swap_b32 %0, %1" : "+v"(c_[5]), "+v"(c_[7]));           \
    f16x8 pf0_, pf1_;                                                         \
    { u32 w_[4] = {c_[0], c_[1], c_[2], c_[3]}; __builtin_memcpy(&pf0_, w_, 16); } \
    { u32 w_[4] = {c_[4], c_[5], c_[6], c_[7]}; __builtin_memcpy(&pf1_, w_, 16); } \
    __builtin_amdgcn_s_setprio(1);                                            \
    O0 = MFMA_F16(VF[0], pf0_, O0);                                           \
    O1 = MFMA_F16(VF[1], pf0_, O1);                                           \
    O2 = MFMA_F16(VF[2], pf0_, O2);                                           \
    O3 = MFMA_F16(VF[3], pf0_, O3);                                           \
    O0 = MFMA_F16(VF[4], pf1_, O0);                                           \
    O1 = MFMA_F16(VF[5], pf1_, O1);                                           \
    O2 = MFMA_F16(VF[6], pf1_, O2);                                           \
    O3 = MFMA_F16(VF[7], pf1_, O3);                                           \
    __builtin_amdgcn_s_setprio(0);                                            \
} while (0)

#define PSTORE_F32(Ot_, t_) do {                                              \
    _Pragma("unroll")                                                         \
    for (int g_ = 0; g_ < 4; ++g_) {                                          \
        float4 v_ = { Ot_[4*g_+0], Ot_[4*g_+1], Ot_[4*g_+2], Ot_[4*g_+3] };   \
        int d_ = (t_) * 32 + 8 * g_ + 4 * hi32;                               \
        *(float4*)(prow32 + d_) = v_;                                         \
    }                                                                         \
} while (0)

#define PSTORE_F16(Ot_, t_) do {                                              \
    _Pragma("unroll")                                                         \
    for (int g_ = 0; g_ < 4; ++g_) {                                          \
        u32 lo_, hi_;                                                         \
        asm("v_cvt_pkrtz_f16_f32 %0, %1, %2"                                  \
            : "=v"(lo_) : "v"(Ot_[4*g_+0]), "v"(Ot_[4*g_+1]));                \
        asm("v_cvt_pkrtz_f16_f32 %0, %1, %2"                                  \
            : "=v"(hi_) : "v"(Ot_[4*g_+2]), "v"(Ot_[4*g_+3]));                \
        int d_ = (t_) * 32 + 8 * g_ + 4 * hi32;                               \
        *(uint2*)(prow16 + d_) = make_uint2(lo_, hi_);                        \
    }                                                                         \
} while (0)

__global__ __launch_bounds__(256, 2)
void attn_main(const float* __restrict__ qin,
               const uint16_t* __restrict__ kws,
               const uint16_t* __restrict__ vws,
               float* __restrict__ out0,       // part-0 un-normalized O (= d_out)
               uint16_t* __restrict__ pout16,  // [3][B_ROWS][128] fp16 parts 1-3
               float2* __restrict__ pml) {     // [4][B_ROWS] (m, l)
    const int lane = threadIdx.x & 63;
    const int wave = threadIdx.x >> 6;
    const int part = blockIdx.x & 3;
    const int tilebase = part * PART_TILES;
    const int q0   = (blockIdx.x >> 2) * 128 + wave * 32;
    const int qrow = q0 + (lane & 31);
    const int hi32 = lane >> 5;

    // Q prep: scale by log2(e), convert to fp16 (B-frag of Sᵀ MFMA).
    f16x8 qh[8];
    {
        const float LOG2E = 1.44269504088896340736f;
        #pragma unroll
        for (int kk = 0; kk < 8; ++kk) {
            const float* src = qin + (size_t)qrow * D_DIM + kk * 16 + hi32 * 8;
            float4 a = *(const float4*)(src);
            float4 b = *(const float4*)(src + 4);
            float xs[8] = {a.x, a.y, a.z, a.w, b.x, b.y, b.z, b.w};
            #pragma unroll
            for (int e = 0; e < 8; ++e)
                qh[kk][e] = (_Float16)(xs[e] * LOG2E);
        }
    }

    f32x16 O0, O1, O2, O3;
    #pragma unroll
    for (int i = 0; i < 16; ++i) { O0[i]=0.f; O1[i]=0.f; O2[i]=0.f; O3[i]=0.f; }
    float m_run = -1e30f, l_run = 0.f;

    const uint16_t* kp = kws + (size_t)tilebase * KTILE_HW + lane * 8;
    const uint16_t* vp = vws + (size_t)tilebase * KTILE_HW + lane * 8;

    f16x8 khA[8], khB[8];
    KLOAD(kp, khA);                     // K(0)

    // 2 tiles per iteration; K register-double-buffered one tile ahead,
    // V issued at visit start (L2 latency covered by QK+softmax).
    #pragma unroll 1
    for (int tp = 0; tp < PART_TILES / 2; ++tp) {
        const int t = 2 * tp;
        {   // ---- tile t (K in khA) ----
            f16x8 vf[8];
            VLOAD(vp + (size_t)t * KTILE_HW, vf);
            KLOAD(kp + (size_t)(t + 1) * KTILE_HW, khB);   // prefetch K(t+1)
            f32x16 s;
            QK(khA, s);
            SMX_PV(s, vf);
        }
        {   // ---- tile t+1 (K in khB) ----
            f16x8 vf[8];
            VLOAD(vp + (size_t)(t + 1) * KTILE_HW, vf);
            if (t + 2 < PART_TILES)
                KLOAD(kp + (size_t)(t + 2) * KTILE_HW, khA);  // prefetch K(t+2)
            f32x16 s;
            QK(khB, s);
            SMX_PV(s, vf);
        }
    }

    // ---- partial store (un-normalized O, plus m,l) ----
    l_run += __shfl_xor(l_run, 32);     // pair-lane partial sums
    if (part == 0) {
        float* prow32 = out0 + (size_t)qrow * D_DIM;
        PSTORE_F32(O0, 0); PSTORE_F32(O1, 1);
        PSTORE_F32(O2, 2); PSTORE_F32(O3, 3);
    } else {
        uint16_t* prow16 = pout16 + ((size_t)(part - 1) * B_ROWS + qrow) * D_DIM;
        PSTORE_F16(O0, 0); PSTORE_F16(O1, 1);
        PSTORE_F16(O2, 2); PSTORE_F16(O3, 3);
    }
    if (lane < 32) {
        pml[(size_t)part * B_ROWS + qrow] = make_float2(m_run, l_run);
    }
}

// ---------------------------------------------------------------------------
// Merge: out = sum_p(P_p * w_p) / sum_p(l_p * w_p), w_p = exp2(m_p - max).
// P0 fp32 in d_out (in-place); P1-3 fp16 in ws.
// ---------------------------------------------------------------------------
__global__ __launch_bounds__(256)
void merge_parts(const uint16_t* __restrict__ pout16,
                 const float2* __restrict__ pml,
                 float* __restrict__ out) {
    int idx  = blockIdx.x * 256 + threadIdx.x;   // 0 .. 2^20-1
    int row  = idx >> 5;
    int c4   = idx & 31;
    float2 a = pml[row];
    float2 b = pml[B_ROWS + row];
    float2 c = pml[2 * B_ROWS + row];
    float2 d = pml[3 * B_ROWS + row];
    float mn = fmaxf(fmaxf(a.x, b.x), fmaxf(c.x, d.x));
    float wa = EXP2F(a.x - mn), wb = EXP2F(b.x - mn);
    float wc = EXP2F(c.x - mn), wd = EXP2F(d.x - mn);
    float rinv = 1.0f / (a.y * wa + b.y * wb + c.y * wc + d.y * wd);

    float4* O = (float4*)(out + (size_t)row * D_DIM) + c4;
    float4 p0 = *O;
    float acc[4] = { p0.x * wa, p0.y * wa, p0.z * wa, p0.w * wa };
    #pragma unroll
    for (int p = 0; p < 3; ++p) {
        const uint16_t* src = pout16 + ((size_t)p * B_ROWS + row) * D_DIM + c4 * 4;
        uint2 q = *(const uint2*)src;
        float2 lo = unpack_h2(q.x), hi = unpack_h2(q.y);
        float w = (p == 0) ? wb : (p == 1 ? wc : wd);
        acc[0] += lo.x * w; acc[1] += lo.y * w;
        acc[2] += hi.x * w; acc[3] += hi.y * w;
    }
    float4 v = { acc[0] * rinv, acc[1] * rinv, acc[2] * rinv, acc[3] * rinv };
    *O = v;
}

extern "C" void kernel_launch(void* const* d_in, const int* in_sizes, int n_in,
                              void* d_out, int out_size, void* d_ws, size_t ws_size,
                              hipStream_t stream) {
    const float* local_stats = (const float*)d_in[0];   // [32768,128] f32
    const float* memory      = (const float*)d_in[1];   // [4096,128]  f32
    float* out = (float*)d_out;                         // [32768,128] f32

    // ws layout: K frags 1MB | V frags 1MB | fp16 parts 1-3 24MB | pml 1MB
    uint16_t* kws    = (uint16_t*)d_ws;
    uint16_t* vws    = kws + 128 * KTILE_HW;
    uint16_t* pout16 = (uint16_t*)((char*)d_ws + 2 * 1024 * 1024);
    float2*   pml    = (float2*)((char*)pout16 + (size_t)3 * B_ROWS * D_DIM * 2);

    prep_frags<<<256, 256, 0, stream>>>(memory, kws, vws);
    attn_main<<<1024, 256, 0, stream>>>(local_stats, kws, vws, out, pout16, pml);
    merge_parts<<<4096, 256, 0, stream>>>(pout16, pml, out);
}

// Round 20
// 99.400 us; speedup vs baseline: 6.8347x; 1.1648x over previous
//
#include <hip/hip_runtime.h>
#include <hip/hip_bf16.h>
#include <stdint.h>

// B=32768 queries, M=4096 memory rows, D=128.
//   logits = Q @ M^T ; attn = softmax(logits) ; out = attn @ M
// v19: exact v13 loop (proven best, 101.4us, absmax 0.03125) + fp16
// part-1 partial store/merge (mechanism proven in v17). v18's fused
// softmax failed correctness for reasons not identifiable by inspection
// -> reverted per methodology. Only the epilogue + merge changed vs v13:
// partial-O traffic 16->8MB on store and on merge read (~2-3us).

typedef float    f32x16 __attribute__((ext_vector_type(16)));
typedef _Float16 f16x8  __attribute__((ext_vector_type(8)));
typedef uint32_t u32;

#define AS1 __attribute__((address_space(1)))
#define AS3 __attribute__((address_space(3)))

#define D_DIM 128
#define B_ROWS 32768
#define TILE_HW 8192      // halfwords per 32-row tile: [K 4096 | V 4096]
#define HALF_TILES 64     // tiles per block

#if __has_builtin(__builtin_amdgcn_exp2f)
#define EXP2F(x) __builtin_amdgcn_exp2f(x)
#else
#define EXP2F(x) exp2f(x)
#endif

__device__ __forceinline__ uint16_t f32_to_f16_bits(float x) {
    _Float16 h = (_Float16)x;
    uint16_t r; __builtin_memcpy(&r, &h, 2);
    return r;
}
__device__ __forceinline__ float2 unpack_h2(u32 w) {
    _Float16 h[2]; __builtin_memcpy(h, &w, 4);
    return make_float2((float)h[0], (float)h[1]);
}

// ---------------------------------------------------------------------------
// Prep: memory -> fragment-linear fp16 tiles in d_ws.
// Per tile mt (16384 B): [0,8K) K frags, [8K,16K) V^T frags.
// ---------------------------------------------------------------------------
__global__ void prep_frags(const float* __restrict__ mem,
                           uint16_t* __restrict__ kv) {
    int t = blockIdx.x * blockDim.x + threadIdx.x;  // 0..65535
    int lane = t & 63;
    int fi = t >> 6;                                // 0..1023
    int f8 = fi & 7, mt = fi >> 3;
    size_t base = (size_t)mt * TILE_HW;
    {   // K fragment
        int m  = mt * 32 + (lane & 31);
        int d0 = f8 * 16 + (lane >> 5) * 8;
        const float* src = mem + (size_t)m * D_DIM + d0;
        #pragma unroll
        for (int e = 0; e < 8; ++e)
            kv[base + f8 * 512 + lane * 8 + e] = f32_to_f16_bits(src[e]);
    }
    {   // V^T fragment
        int dt = fi & 3, ks = (fi >> 2) & 1;
        int d  = dt * 32 + (lane & 31);
        int m0 = mt * 32 + ks * 16 + (lane >> 5) * 8;
        #pragma unroll
        for (int e = 0; e < 8; ++e)
            kv[base + 4096 + f8 * 512 + lane * 8 + e] =
                f32_to_f16_bits(mem[(size_t)(m0 + e) * D_DIM + d]);
    }
}

// ---------------------------------------------------------------------------
// Main kernel: 512 blocks x 256 threads (4 waves). Block bx: q-chunk bx>>1,
// memory half bx&1 (64 tiles). LDS 4 x 16KB buffers, 2 tiles per barrier.
// ---------------------------------------------------------------------------

#define STAGE(t_, wb_) do {                                                   \
    const char* g_ = (const char*)(kv + (size_t)(tilebase + (t_)) * TILE_HW); \
    char* l_ = (char*)&sbuf[wb_][0];                                          \
    _Pragma("unroll")                                                         \
    for (int j_ = 0; j_ < 4; ++j_) {                                          \
        int ch_ = wave * 4 + j_;                                              \
        __builtin_amdgcn_global_load_lds(                                     \
            (const AS1 char*)(g_ + ch_ * 1024 + lane * 16),                   \
            (AS3 char*)(l_ + ch_ * 1024), 16, 0, 0);                          \
    }                                                                         \
} while (0)

#define MFMA_F16(a_, b_, c_) __builtin_amdgcn_mfma_f32_32x32x16_f16(a_, b_, c_, 0, 0, 0)

// QK^T for one tile: batch 8 K reads, two 4-deep chains -> s_.
#define QK(bp_, s_) do {                                                      \
    f16x8 kh_[8];                                                             \
    _Pragma("unroll")                                                         \
    for (int kk_ = 0; kk_ < 8; ++kk_)                                         \
        kh_[kk_] = *(const f16x8*)((bp_) + kk_ * 512);                        \
    f32x16 sA_, sB_;                                                          \
    _Pragma("unroll")                                                         \
    for (int i_ = 0; i_ < 16; ++i_) { sA_[i_] = 0.f; sB_[i_] = 0.f; }         \
    sA_ = MFMA_F16(kh_[0], qh[0], sA_);                                       \
    sB_ = MFMA_F16(kh_[1], qh[1], sB_);                                       \
    sA_ = MFMA_F16(kh_[2], qh[2], sA_);                                       \
    sB_ = MFMA_F16(kh_[3], qh[3], sB_);                                       \
    sA_ = MFMA_F16(kh_[4], qh[4], sA_);                                       \
    sB_ = MFMA_F16(kh_[5], qh[5], sB_);                                       \
    sA_ = MFMA_F16(kh_[6], qh[6], sA_);                                       \
    sB_ = MFMA_F16(kh_[7], qh[7], sB_);                                       \
    s_ = sA_ + sB_;                                                           \
} while (0)

// Online softmax on s_ (Sᵀ layout) then PV of the same tile.
#define SMX_PV(s_, bp_) do {                                                  \
    float a0=fmaxf(s_[0],s_[1]),  a1=fmaxf(s_[2],s_[3]);                      \
    float a2=fmaxf(s_[4],s_[5]),  a3=fmaxf(s_[6],s_[7]);                      \
    float a4=fmaxf(s_[8],s_[9]),  a5=fmaxf(s_[10],s_[11]);                    \
    float a6=fmaxf(s_[12],s_[13]),a7=fmaxf(s_[14],s_[15]);                    \
    float tmax = fmaxf(fmaxf(fmaxf(a0,a1),fmaxf(a2,a3)),                      \
                       fmaxf(fmaxf(a4,a5),fmaxf(a6,a7)));                     \
    tmax = fmaxf(tmax, __shfl_xor(tmax, 32));                                 \
    if (__any(tmax > m_run + 8.0f)) {     /* defer-max (T13) */               \
        float mn = fmaxf(m_run, tmax);                                        \
        float fr = EXP2F(m_run - mn);                                         \
        m_run = mn; l_run *= fr;                                              \
        _Pragma("unroll")                                                     \
        for (int r_ = 0; r_ < 16; ++r_) {                                     \
            O0[r_] *= fr; O1[r_] *= fr; O2[r_] *= fr; O3[r_] *= fr;           \
        }                                                                     \
    }                                                                         \
    _Pragma("unroll")                                                         \
    for (int r_ = 0; r_ < 16; ++r_) s_[r_] = EXP2F(s_[r_] - m_run);           \
    { float q0s=s_[0]+s_[1],  q1s=s_[2]+s_[3],  q2s=s_[4]+s_[5],  q3s=s_[6]+s_[7];   \
      float q4s=s_[8]+s_[9],  q5s=s_[10]+s_[11],q6s=s_[12]+s_[13],q7s=s_[14]+s_[15]; \
      l_run += ((q0s+q1s)+(q2s+q3s)) + ((q4s+q5s)+(q6s+q7s)); }               \
    u32 c_[8];                                                                \
    _Pragma("unroll")                                                         \
    for (int j_ = 0; j_ < 8; ++j_)                                            \
        asm("v_cvt_pkrtz_f16_f32 %0, %1, %2"                                  \
            : "=v"(c_[j_]) : "v"(s_[2*j_]), "v"(s_[2*j_+1]));                 \
    asm("v_permlane32_swap_b32 %0, %1" : "+v"(c_[0]), "+v"(c_[2]));           \
    asm("v_permlane32_swap_b32 %0, %1" : "+v"(c_[1]), "+v"(c_[3]));           \
    asm("v_permlane32_swap_b32 %0, %1" : "+v"(c_[4]), "+v"(c_[6]));           \
    asm("v_permlane32_swap_b32 %0, %1" : "+v"(c_[5]), "+v"(c_[7]));           \
    f16x8 pf0_, pf1_;                                                         \
    { u32 w_[4] = {c_[0], c_[1], c_[2], c_[3]}; __builtin_memcpy(&pf0_, w_, 16); } \
    { u32 w_[4] = {c_[4], c_[5], c_[6], c_[7]}; __builtin_memcpy(&pf1_, w_, 16); } \
    f16x8 vf_[8];                                                             \
    _Pragma("unroll")                                                         \
    for (int f_ = 0; f_ < 8; ++f_)                                            \
        vf_[f_] = *(const f16x8*)((bp_) + 4096 + f_ * 512);                   \
    O0 = MFMA_F16(vf_[0], pf0_, O0);                                          \
    O1 = MFMA_F16(vf_[1], pf0_, O1);                                          \
    O2 = MFMA_F16(vf_[2], pf0_, O2);                                          \
    O3 = MFMA_F16(vf_[3], pf0_, O3);                                          \
    O0 = MFMA_F16(vf_[4], pf1_, O0);                                          \
    O1 = MFMA_F16(vf_[5], pf1_, O1);                                          \
    O2 = MFMA_F16(vf_[6], pf1_, O2);                                          \
    O3 = MFMA_F16(vf_[7], pf1_, O3);                                          \
} while (0)

#define PSTORE_F32(Ot_, t_) do {                                              \
    _Pragma("unroll")                                                         \
    for (int g_ = 0; g_ < 4; ++g_) {                                          \
        float4 v_ = { Ot_[4*g_+0], Ot_[4*g_+1], Ot_[4*g_+2], Ot_[4*g_+3] };   \
        int d_ = (t_) * 32 + 8 * g_ + 4 * hi32;                               \
        *(float4*)(prow32 + d_) = v_;                                         \
    }                                                                         \
} while (0)

#define PSTORE_F16(Ot_, t_) do {                                              \
    _Pragma("unroll")                                                         \
    for (int g_ = 0; g_ < 4; ++g_) {                                          \
        u32 lo_, hi_;                                                         \
        asm("v_cvt_pkrtz_f16_f32 %0, %1, %2"                                  \
            : "=v"(lo_) : "v"(Ot_[4*g_+0]), "v"(Ot_[4*g_+1]));                \
        asm("v_cvt_pkrtz_f16_f32 %0, %1, %2"                                  \
            : "=v"(hi_) : "v"(Ot_[4*g_+2]), "v"(Ot_[4*g_+3]));                \
        int d_ = (t_) * 32 + 8 * g_ + 4 * hi32;                               \
        *(uint2*)(prow16 + d_) = make_uint2(lo_, hi_);                        \
    }                                                                         \
} while (0)

__global__ __launch_bounds__(256, 2)
void attn_main(const float* __restrict__ qin,
               const uint16_t* __restrict__ kv,
               float* __restrict__ out0,        // part-0 un-normalized O (= d_out)
               uint16_t* __restrict__ pout1,    // [B_ROWS][128] fp16 part-1 partial
               float2* __restrict__ pml) {      // [2][B_ROWS] (m, l)
    __shared__ uint16_t sbuf[4][TILE_HW];   // 4 x 16 KB = 64 KB

    const int lane = threadIdx.x & 63;
    const int wave = threadIdx.x >> 6;
    const int half = blockIdx.x & 1;
    const int tilebase = half * HALF_TILES;
    const int q0   = (blockIdx.x >> 1) * 128 + wave * 32;
    const int qrow = q0 + (lane & 31);
    const int hi32 = lane >> 5;

    // Q prep: scale by log2(e), convert to fp16 (B-frag of Sᵀ MFMA).
    f16x8 qh[8];
    {
        const float LOG2E = 1.44269504088896340736f;
        #pragma unroll
        for (int kk = 0; kk < 8; ++kk) {
            const float* src = qin + (size_t)qrow * D_DIM + kk * 16 + hi32 * 8;
            float4 a = *(const float4*)(src);
            float4 b = *(const float4*)(src + 4);
            float xs[8] = {a.x, a.y, a.z, a.w, b.x, b.y, b.z, b.w};
            #pragma unroll
            for (int e = 0; e < 8; ++e)
                qh[kk][e] = (_Float16)(xs[e] * LOG2E);
        }
    }

    f32x16 O0, O1, O2, O3;
    #pragma unroll
    for (int i = 0; i < 16; ++i) { O0[i]=0.f; O1[i]=0.f; O2[i]=0.f; O3[i]=0.f; }
    float m_run = -1e30f, l_run = 0.f;

    STAGE(0, 0);
    STAGE(1, 1);
    __syncthreads();

    // 2 tiles per barrier interval (exact v13 schedule).
    #pragma unroll 1
    for (int t = 0; t < HALF_TILES; t += 2) {
        if (t + 2 < HALF_TILES) STAGE(t + 2, (t + 2) & 3);
        if (t + 3 < HALF_TILES) STAGE(t + 3, (t + 3) & 3);
        const uint16_t* bp0 = &sbuf[t & 3][0] + lane * 8;
        const uint16_t* bp1 = &sbuf[(t + 1) & 3][0] + lane * 8;

        f32x16 s0, s1;
        QK(bp0, s0);          // tile t
        QK(bp1, s1);          // tile t+1 — MFMAs overlap softmax(t) below
        SMX_PV(s0, bp0);      // softmax(t) + PV(t)
        SMX_PV(s1, bp1);      // softmax(t+1) + PV(t+1)
        __syncthreads();
    }

    // ---- partial store (un-normalized O, plus m,l) ----
    l_run += __shfl_xor(l_run, 32);     // pair-lane partial sums
    if (half == 0) {
        float* prow32 = out0 + (size_t)qrow * D_DIM;
        PSTORE_F32(O0, 0); PSTORE_F32(O1, 1);
        PSTORE_F32(O2, 2); PSTORE_F32(O3, 3);
    } else {
        uint16_t* prow16 = pout1 + (size_t)qrow * D_DIM;
        PSTORE_F16(O0, 0); PSTORE_F16(O1, 1);
        PSTORE_F16(O2, 2); PSTORE_F16(O3, 3);
    }
    if (lane < 32) {
        pml[(size_t)half * B_ROWS + qrow] = make_float2(m_run, l_run);
    }
}

// ---------------------------------------------------------------------------
// Merge: out = (P0*w0 + P1*w1) / (l0*w0 + l1*w1), w_i = exp2(m_i - max).
// P0 fp32 in d_out (in-place); P1 fp16 in ws (v17-proven unpack path).
// ---------------------------------------------------------------------------
__global__ __launch_bounds__(256)
void merge_halves(const uint16_t* __restrict__ pout1,
                  const float2* __restrict__ pml,
                  float* __restrict__ out) {
    int idx  = blockIdx.x * 256 + threadIdx.x;   // 0 .. 2^20-1
    int row  = idx >> 5;
    int c4   = idx & 31;
    float2 a = pml[row];
    float2 b = pml[B_ROWS + row];
    float mn = fmaxf(a.x, b.x);
    float wa = EXP2F(a.x - mn);
    float wb = EXP2F(b.x - mn);
    float rinv = 1.0f / (a.y * wa + b.y * wb);
    float4* O = (float4*)(out + (size_t)row * D_DIM) + c4;
    float4 p0 = *O;
    const uint16_t* src = pout1 + (size_t)row * D_DIM + c4 * 4;
    uint2 q = *(const uint2*)src;
    float2 lo = unpack_h2(q.x), hi = unpack_h2(q.y);
    float4 v;
    v.x = (p0.x * wa + lo.x * wb) * rinv;
    v.y = (p0.y * wa + lo.y * wb) * rinv;
    v.z = (p0.z * wa + hi.x * wb) * rinv;
    v.w = (p0.w * wa + hi.y * wb) * rinv;
    *O = v;
}

extern "C" void kernel_launch(void* const* d_in, const int* in_sizes, int n_in,
                              void* d_out, int out_size, void* d_ws, size_t ws_size,
                              hipStream_t stream) {
    const float* local_stats = (const float*)d_in[0];   // [32768,128] f32
    const float* memory      = (const float*)d_in[1];   // [4096,128]  f32
    float* out = (float*)d_out;                         // [32768,128] f32

    // ws layout: kv frags 2MB | part-1 fp16 partial O 8MB | pml 0.5MB
    uint16_t* kv    = (uint16_t*)d_ws;
    uint16_t* pout1 = (uint16_t*)((char*)d_ws + 2 * 1024 * 1024);
    float2*   pml   = (float2*)((char*)pout1 + (size_t)B_ROWS * D_DIM * 2);

    prep_frags<<<256, 256, 0, stream>>>(memory, kv);
    attn_main<<<512, 256, 0, stream>>>(local_stats, kv, out, pout1, pml);
    merge_halves<<<4096, 256, 0, stream>>>(pout1, pml, out);
}